// Round 8
// baseline (4088.951 us; speedup 1.0000x reference)
//
#include <hip/hip_runtime.h>
#include <hip/hip_bf16.h>

typedef unsigned short u16;
typedef unsigned int u32;
typedef __bf16 bf16x8 __attribute__((ext_vector_type(8)));
typedef float f32x4 __attribute__((ext_vector_type(4)));

#if __has_builtin(__builtin_amdgcn_exp2f)
#define FEXP2 __builtin_amdgcn_exp2f
#else
#define FEXP2 exp2f
#endif

#if __has_builtin(__builtin_amdgcn_rcpf)
#define FRCP __builtin_amdgcn_rcpf
#else
#define FRCP(x) (1.0f / (x))
#endif

#define QSCALE 0.1803368801f /* 0.125 * log2(e): softmax done in exp2 domain */

__device__ __forceinline__ u16 f2bf(float f) {
  __hip_bfloat16 h = __float2bfloat16(f);
  return __builtin_bit_cast(u16, h);
}

// fast RNE pack of two finite non-negative floats to packed bf16x2
__device__ __forceinline__ u32 pack2_bf16(float a, float b) {
  u32 ua = __builtin_bit_cast(u32, a);
  ua += 0x7FFFu + ((ua >> 16) & 1u);
  u32 ub = __builtin_bit_cast(u32, b);
  ub += 0x7FFFu + ((ub >> 16) & 1u);
  return (ua >> 16) | (ub & 0xFFFF0000u);
}

__device__ __forceinline__ void load_lds16(const u16* g, u16* l) {
  __builtin_amdgcn_global_load_lds((const __attribute__((address_space(1))) void*)g,
                                   (__attribute__((address_space(3))) void*)l, 16, 0, 0);
}

// ---------------- transpose + fp32->bf16: src[R][C] -> dst[C][R] ----------------
__global__ __launch_bounds__(256) void tconv_kernel(const float* __restrict__ src,
                                                    u16* __restrict__ dst, int R, int C) {
  __shared__ float tile[32][33];
  int bx = blockIdx.x * 32, by = blockIdx.y * 32;
  int tx = threadIdx.x, ty = threadIdx.y;
#pragma unroll
  for (int i = 0; i < 4; ++i)
    tile[ty + 8 * i][tx] = src[(size_t)(by + ty + 8 * i) * C + bx + tx];
  __syncthreads();
#pragma unroll
  for (int i = 0; i < 4; ++i)
    dst[(size_t)(bx + ty + 8 * i) * R + by + tx] = f2bf(tile[tx][ty + 8 * i]);
}

// ---------------- LayerNorm row of 1024: fp32 in -> bf16 out ----------------
__global__ __launch_bounds__(256) void ln_kernel(const float* __restrict__ src,
                                                 u16* __restrict__ dst,
                                                 const float* __restrict__ gamma,
                                                 const float* __restrict__ beta) {
  int row = blockIdx.x, tid = threadIdx.x;
  const float4 v = ((const float4*)(src + (size_t)row * 1024))[tid];
  float s = v.x + v.y + v.z + v.w;
  float q = v.x * v.x + v.y * v.y + v.z * v.z + v.w * v.w;
#pragma unroll
  for (int off = 32; off >= 1; off >>= 1) {
    s += __shfl_down(s, off, 64);
    q += __shfl_down(q, off, 64);
  }
  __shared__ float red[8];
  if ((tid & 63) == 0) { red[(tid >> 6) * 2] = s; red[(tid >> 6) * 2 + 1] = q; }
  __syncthreads();
  s = red[0] + red[2] + red[4] + red[6];
  q = red[1] + red[3] + red[5] + red[7];
  float mean = s * (1.0f / 1024.0f);
  float var = q * (1.0f / 1024.0f) - mean * mean;
  float rstd = rsqrtf(var + 1e-5f);
  float4 g = ((const float4*)gamma)[tid];
  float4 b = ((const float4*)beta)[tid];
  ushort4 o;
  o.x = f2bf((v.x - mean) * rstd * g.x + b.x);
  o.y = f2bf((v.y - mean) * rstd * g.y + b.y);
  o.z = f2bf((v.z - mean) * rstd * g.z + b.z);
  o.w = f2bf((v.w - mean) * rstd * g.w + b.w);
  *(ushort4*)(dst + (size_t)row * 1024 + tid * 4) = o;
}

// shared epilogue
template <int MODE>
__device__ __forceinline__ void epilogue_elem(float v, int row, int col, int N,
                                              const float* __restrict__ bias,
                                              const float* __restrict__ resid,
                                              void* __restrict__ outp,
                                              void* __restrict__ outp2,
                                              void* __restrict__ outp3) {
  if constexpr (MODE == 0) {
    const int slotc = col >> 6;      // 0..47
    const int ty = slotc >> 4;       // 0=Q,1=K,2=V
    const int h = slotc & 15, d = col & 63;
    const int bb = row >> 11, s = row & 2047;
    if (ty == 0) {
      ((u16*)outp)[(((size_t)(bb * 16 + h)) * 2048 + s) * 64 + d] = f2bf(v * QSCALE);
    } else if (ty == 1) {
      ((u16*)outp2)[(((size_t)(bb * 16 + h)) * 2048 + s) * 64 + d] = f2bf(v);
    } else {
      const int spos = (s & ~31) | ((s & 15) << 1) | ((s >> 4) & 1);
      ((u16*)outp3)[(((size_t)(bb * 16 + h)) * 64 + d) * 2048 + spos] = f2bf(v);
    }
  } else if constexpr (MODE == 3) {
    ((float*)outp)[(size_t)row * N + col] = v + bias[col] + resid[(size_t)row * N + col];
  } else if constexpr (MODE == 4) {
    // gelu_tanh(u) = u * sigmoid(2c), c = 0.79788456*u*(1+0.044715*u^2)
    float u = v + bias[col];
    float c = u * (0.7978845608f + 0.0356774081f * u * u);
    float t = FEXP2(c * -2.885390082f);  // exp(-2c)
    ((u16*)outp)[(size_t)row * N + col] = f2bf(u * FRCP(1.0f + t));
  } else if constexpr (MODE == 5) {
    ((float*)outp)[(size_t)row * N + col] = v + bias[col] + resid[(size_t)row * N + col];
  }
}

// -------- staged GEMM: 128 x BN tile, BK=64 as two m97-layout 32-K halves --------
template <int MODE, int BN>
__global__ __launch_bounds__(256, 2) void gemm2(const u16* __restrict__ A,
                                                const u16* __restrict__ BT,
                                                int M, int N, int K, int nbx,
                                                const float* __restrict__ bias,
                                                const float* __restrict__ resid,
                                                void* __restrict__ outp,
                                                void* __restrict__ outp2,
                                                void* __restrict__ outp3) {
  constexpr int NJ = BN / 32;  // j-fragments per wave
  const int tid = threadIdx.x, lane = tid & 63, wave = tid >> 6;
  const int l16 = lane & 15, quad = lane >> 4;
  const int id = blockIdx.x, xcd = id & 7, s = id >> 3;
  const int by = xcd * 4 + s / nbx, bx = s - (s / nbx) * nbx;
  const int mblk = by * 128, nblk = bx * BN;
  const int m0w = (wave >> 1) * 64, n0w = (wave & 1) * (BN / 2);

  __shared__ u16 Ab[2][128 * 32];
  __shared__ u16 Bb[2][BN * 32];

  f32x4 acc[4][NJ];
#pragma unroll
  for (int i = 0; i < 4; ++i)
#pragma unroll
    for (int j = 0; j < NJ; ++j)
#pragma unroll
      for (int r = 0; r < 4; ++r) acc[i][j][r] = 0.0f;

  const int srow = lane >> 2, schunk = lane & 3;
  const u16* gA = A + (size_t)(mblk + wave * 32 + srow) * K + schunk * 8;
  u16* lA0 = Ab[0] + (wave * 32) * 32;
  u16* lA1 = Ab[1] + (wave * 32) * 32;
  const int bwrows = (BN == 128) ? wave * 32 : wave * 16;
  const u16* gB = BT + (size_t)(nblk + bwrows + srow) * K + schunk * 8;
  u16* lB0 = Bb[0] + bwrows * 32;
  u16* lB1 = Bb[1] + bwrows * 32;

  for (int k0 = 0; k0 < K; k0 += 64) {
    __syncthreads();
    load_lds16(gA + k0, lA0);
    load_lds16(gA + 16 * (size_t)K + k0, lA0 + 16 * 32);
    load_lds16(gA + k0 + 32, lA1);
    load_lds16(gA + 16 * (size_t)K + k0 + 32, lA1 + 16 * 32);
    if constexpr (BN == 128) {
      load_lds16(gB + k0, lB0);
      load_lds16(gB + 16 * (size_t)K + k0, lB0 + 16 * 32);
      load_lds16(gB + k0 + 32, lB1);
      load_lds16(gB + 16 * (size_t)K + k0 + 32, lB1 + 16 * 32);
    } else {
      load_lds16(gB + k0, lB0);
      load_lds16(gB + k0 + 32, lB1);
    }
    asm volatile("s_waitcnt vmcnt(0)" ::: "memory");
    __syncthreads();

#pragma unroll
    for (int h = 0; h < 2; ++h) {
      bf16x8 af[4], bfr[NJ];
#pragma unroll
      for (int i = 0; i < 4; ++i)
        af[i] = *(const bf16x8*)(Ab[h] + (m0w + i * 16 + l16) * 32 + quad * 8);
#pragma unroll
      for (int j = 0; j < NJ; ++j)
        bfr[j] = *(const bf16x8*)(Bb[h] + (n0w + j * 16 + l16) * 32 + quad * 8);
#pragma unroll
      for (int i = 0; i < 4; ++i)
#pragma unroll
        for (int j = 0; j < NJ; ++j)
          acc[i][j] = __builtin_amdgcn_mfma_f32_16x16x32_bf16(af[i], bfr[j], acc[i][j], 0, 0, 0);
    }
  }

#pragma unroll
  for (int i = 0; i < 4; ++i)
#pragma unroll
    for (int j = 0; j < NJ; ++j) {
      const int col = nblk + n0w + j * 16 + l16;
#pragma unroll
      for (int r = 0; r < 4; ++r)
        epilogue_elem<MODE>(acc[i][j][r], mblk + m0w + i * 16 + quad * 4 + r, col, N,
                            bias, resid, outp, outp2, outp3);
    }
}

// ---------------- attention helpers ----------------
__device__ __forceinline__ void qk_scores(const bf16x8 (&qf)[2][2],
                                          const bf16x8 (&kf)[2][2],
                                          f32x4 (&sc)[2][2]) {
#pragma unroll
  for (int rf = 0; rf < 2; ++rf)
#pragma unroll
    for (int st = 0; st < 2; ++st) {
#pragma unroll
      for (int r = 0; r < 4; ++r) sc[rf][st][r] = 0.0f;
#pragma unroll
      for (int kk = 0; kk < 2; ++kk)
        sc[rf][st] = __builtin_amdgcn_mfma_f32_16x16x32_bf16(qf[kk == 0 ? rf : rf][kk], kf[st][kk], sc[rf][st], 0, 0, 0);
    }
}

__device__ __forceinline__ void emit_exp(const f32x4 (&sc)[2][2], bool masked,
                                         int l16, int quad, u16* pw) {
#pragma unroll
  for (int rf = 0; rf < 2; ++rf)
#pragma unroll
    for (int r = 0; r < 4; ++r) {
      float s0 = sc[rf][0][r], s1 = sc[rf][1][r];
      if (masked) {
        const int rel = rf * 16 + quad * 4 + r;
        if (l16 > rel) s0 = -INFINITY;
        if (16 + l16 > rel) s1 = -INFINITY;
      }
      *(u32*)(pw + (rf * 16 + quad * 4 + r) * 40 + l16 * 2) =
          pack2_bf16(FEXP2(s0), FEXP2(s1));
    }
}

// ---------------- flash attention: causal, HEAD_DIM=64, S=2048 ----------------
// 512 blocks x 256 threads; waves 0-1 -> q-tile (31-pr), waves 2-3 -> q-tile pr
// (uniform work). Software-pipelined K-loop: scores(t+1) and PV(t) issue as one
// MFMA burst while exp(t+1) VALU overlaps; P double-buffered in LDS, K/V
// fragments double-buffered in registers with 2-deep global prefetch.
__global__ __launch_bounds__(256) void attn_kernel(const u16* __restrict__ Q,
                                                   const u16* __restrict__ Kb,
                                                   const u16* __restrict__ VT,
                                                   u16* __restrict__ ctx) {
  const int tid = threadIdx.x, lane = tid & 63, wave = tid >> 6;
  const int l16 = lane & 15, quad = lane >> 4;
  const int id = blockIdx.x, xcd = id & 7, slot = id >> 3;
  const int bh = xcd + 8 * (slot & 3);   // 4 bh per XCD -> K/V stay L2-local
  const int pr = slot >> 2;              // 0..15
  const int qt = (wave < 2) ? (31 - pr) : pr;
  const int b = bh >> 4, hh = bh & 15;
  const int q0 = qt * 64 + (wave & 1) * 32;

  const u16* qp = Q + (size_t)bh * 2048 * 64;
  const u16* kp = Kb + (size_t)bh * 2048 * 64;
  const u16* vp = VT + (size_t)bh * 64 * 2048;

  bf16x8 qf[2][2];
#pragma unroll
  for (int rf = 0; rf < 2; ++rf)
#pragma unroll
    for (int kk = 0; kk < 2; ++kk)
      qf[rf][kk] = *(const bf16x8*)(qp + (size_t)(q0 + rf * 16 + l16) * 64 + kk * 32 + quad * 8);

  f32x4 o[2][4], lac[2];
#pragma unroll
  for (int rf = 0; rf < 2; ++rf) {
#pragma unroll
    for (int r = 0; r < 4; ++r) lac[rf][r] = 0.0f;
#pragma unroll
    for (int dt = 0; dt < 4; ++dt)
#pragma unroll
      for (int r = 0; r < 4; ++r) o[rf][dt][r] = 0.0f;
  }

  bf16x8 onef;
#pragma unroll
  for (int i = 0; i < 8; ++i) onef[i] = (__bf16)1.0f;

  __shared__ u16 pbuf[4][2][32 * 40];  // per-wave double-buffered P tile (20 KB)

  const int nfull = q0 >> 5;  // tiles [0, nfull) unmasked; tile nfull is diagonal

  // K/V register double-buffers, 2-deep prefetch
  bf16x8 kfb[2][2][2], vfb[2][4];
#pragma unroll
  for (int st = 0; st < 2; ++st)
#pragma unroll
    for (int kk = 0; kk < 2; ++kk)
      kfb[0][st][kk] = *(const bf16x8*)(kp + (size_t)(st * 16 + l16) * 64 + kk * 32 + quad * 8);
#pragma unroll
  for (int dt = 0; dt < 4; ++dt)
    vfb[0][dt] = *(const bf16x8*)(vp + (size_t)(dt * 16 + l16) * 2048 + quad * 8);
  const int t1 = (nfull >= 1) ? 32 : 0;
#pragma unroll
  for (int st = 0; st < 2; ++st)
#pragma unroll
    for (int kk = 0; kk < 2; ++kk)
      kfb[1][st][kk] = *(const bf16x8*)(kp + (size_t)(t1 + st * 16 + l16) * 64 + kk * 32 + quad * 8);
#pragma unroll
  for (int dt = 0; dt < 4; ++dt)
    vfb[1][dt] = *(const bf16x8*)(vp + (size_t)(dt * 16 + l16) * 2048 + t1 + quad * 8);

  f32x4 sc[2][2];
  qk_scores(qf, kfb[0], sc);
  emit_exp(sc, nfull == 0, l16, quad, pbuf[wave][0]);

  for (int kt = 0; kt <= nfull; ++kt) {
    const int cur = kt & 1;
    u16* pwc = pbuf[wave][cur];
    u16* pwn = pbuf[wave][cur ^ 1];

    if (kt < nfull) qk_scores(qf, kfb[cur ^ 1], sc);  // scores(kt+1), MFMA pipe

    asm volatile("s_waitcnt lgkmcnt(0)" ::: "memory");
#pragma unroll
    for (int rf = 0; rf < 2; ++rf) {  // PV(kt), MFMA pipe
      bf16x8 pf = *(const bf16x8*)(pwc + (rf * 16 + l16) * 40 + quad * 8);
      lac[rf] = __builtin_amdgcn_mfma_f32_16x16x32_bf16(pf, onef, lac[rf], 0, 0, 0);
#pragma unroll
      for (int dt = 0; dt < 4; ++dt)
        o[rf][dt] = __builtin_amdgcn_mfma_f32_16x16x32_bf16(pf, vfb[cur][dt], o[rf][dt], 0, 0, 0);
    }

    if (kt < nfull) {
      // prefetch tile kt+2 (clamped) into the just-freed buffer
      const int kn = (kt + 2 <= nfull ? kt + 2 : nfull) * 32;
#pragma unroll
      for (int st = 0; st < 2; ++st)
#pragma unroll
        for (int kk = 0; kk < 2; ++kk)
          kfb[cur][st][kk] = *(const bf16x8*)(kp + (size_t)(kn + st * 16 + l16) * 64 + kk * 32 + quad * 8);
#pragma unroll
      for (int dt = 0; dt < 4; ++dt)
        vfb[cur][dt] = *(const bf16x8*)(vp + (size_t)(dt * 16 + l16) * 2048 + kn + quad * 8);
      emit_exp(sc, (kt + 1) == nfull, l16, quad, pwn);  // exp(kt+1), VALU overlaps MFMA drain
    }
  }

#pragma unroll
  for (int rf = 0; rf < 2; ++rf)
#pragma unroll
    for (int r = 0; r < 4; ++r) {
      const float inv = 1.0f / lac[rf][r];
      const int row = q0 + rf * 16 + quad * 4 + r;
#pragma unroll
      for (int dt = 0; dt < 4; ++dt) {
        const int col = dt * 16 + l16;
        ctx[((size_t)(b * 2048 + row)) * 1024 + hh * 64 + col] = f2bf(o[rf][dt][r] * inv);
      }
    }
}

// ---------------- launch ----------------
extern "C" void kernel_launch(void* const* d_in, const int* in_sizes, int n_in,
                              void* d_out, int out_size, void* d_ws, size_t ws_size,
                              hipStream_t stream) {
  (void)in_sizes; (void)n_in; (void)out_size; (void)ws_size;
  const float* x    = (const float*)d_in[0];
  const float* g1   = (const float*)d_in[1];
  const float* s1   = (const float*)d_in[2];
  const float* wq   = (const float*)d_in[3];
  const float* wk   = (const float*)d_in[4];
  const float* wv   = (const float*)d_in[5];
  const float* wo   = (const float*)d_in[6];
  const float* bo   = (const float*)d_in[7];
  const float* g2   = (const float*)d_in[8];
  const float* s2   = (const float*)d_in[9];
  const float* w1   = (const float*)d_in[10];
  const float* b1   = (const float*)d_in[11];
  const float* w2   = (const float*)d_in[12];
  const float* b2   = (const float*)d_in[13];

  char* ws = (char*)d_ws;
  u16* wqkvT = (u16*)(ws + 0);          // 6 MB  [3072][1024]
  u16* woT   = (u16*)(ws + 6291456);    // 2 MB
  u16* w1T   = (u16*)(ws + 8388608);    // 8 MB  [4096][1024]
  u16* w2T   = (u16*)(ws + 16777216);   // 8 MB  [1024][4096]
  u16* xn    = (u16*)(ws + 25165824);   // 8 MB  (reused as y)
  u16* qb    = (u16*)(ws + 33554432);   // 8 MB
  u16* kb    = (u16*)(ws + 41943040);   // 8 MB
  u16* vT    = (u16*)(ws + 50331648);   // 8 MB
  u16* ctx   = (u16*)(ws + 58720256);   // 8 MB
  u16* f     = (u16*)(ws + 33554432);   // 32 MB, aliases qb..ctx (dead by FFN1)
  float* h   = (float*)(ws + 67108864); // 16 MB
  u16* y     = xn;

  dim3 tb(32, 8);
  tconv_kernel<<<dim3(32, 32), tb, 0, stream>>>(wq, wqkvT, 1024, 1024);
  tconv_kernel<<<dim3(32, 32), tb, 0, stream>>>(wk, wqkvT + 1024 * 1024, 1024, 1024);
  tconv_kernel<<<dim3(32, 32), tb, 0, stream>>>(wv, wqkvT + 2048 * 1024, 1024, 1024);
  tconv_kernel<<<dim3(32, 32), tb, 0, stream>>>(wo, woT, 1024, 1024);
  tconv_kernel<<<dim3(128, 32), tb, 0, stream>>>(w1, w1T, 1024, 4096);
  tconv_kernel<<<dim3(32, 128), tb, 0, stream>>>(w2, w2T, 4096, 1024);

  // LN1
  ln_kernel<<<4096, 256, 0, stream>>>(x, xn, g1, s1);

  // fused QKV projection (N=3072), nbx=24
  gemm2<0, 128><<<768, 256, 0, stream>>>(xn, wqkvT, 4096, 3072, 1024, 24,
                                         nullptr, nullptr, qb, kb, vT);

  // attention: 512 uniform blocks, pipelined
  attn_kernel<<<512, 256, 0, stream>>>(qb, kb, vT, ctx);

  // output projection + bias + residual(x) -> h (fp32), nbx=16
  gemm2<3, 64><<<512, 256, 0, stream>>>(ctx, woT, 4096, 1024, 1024, 16, bo, x, h,
                                        nullptr, nullptr);

  // LN2
  ln_kernel<<<4096, 256, 0, stream>>>(h, y, g2, s2);

  // FFN1 (N=4096), nbx=32
  gemm2<4, 128><<<1024, 256, 0, stream>>>(y, w1T, 4096, 4096, 1024, 32,
                                          b1, nullptr, f, nullptr, nullptr);
  // FFN2 (N=1024, K=4096), nbx=16
  gemm2<5, 64><<<512, 256, 0, stream>>>(f, w2T, 4096, 1024, 4096, 16, b2, h,
                                        (float*)d_out, nullptr, nullptr);
}

// Round 9
// 366.068 us; speedup vs baseline: 11.1699x; 11.1699x over previous
//
#include <hip/hip_runtime.h>
#include <hip/hip_bf16.h>

typedef unsigned short u16;
typedef unsigned int u32;
typedef __bf16 bf16x8 __attribute__((ext_vector_type(8)));
typedef float f32x4 __attribute__((ext_vector_type(4)));

#if __has_builtin(__builtin_amdgcn_exp2f)
#define FEXP2 __builtin_amdgcn_exp2f
#else
#define FEXP2 exp2f
#endif

#if __has_builtin(__builtin_amdgcn_rcpf)
#define FRCP __builtin_amdgcn_rcpf
#else
#define FRCP(x) (1.0f / (x))
#endif

#define QSCALE 0.1803368801f /* 0.125 * log2(e): softmax done in exp2 domain */

__device__ __forceinline__ u16 f2bf(float f) {
  __hip_bfloat16 h = __float2bfloat16(f);
  return __builtin_bit_cast(u16, h);
}

// fast RNE pack of two finite non-negative floats to packed bf16x2
__device__ __forceinline__ u32 pack2_bf16(float a, float b) {
  u32 ua = __builtin_bit_cast(u32, a);
  ua += 0x7FFFu + ((ua >> 16) & 1u);
  u32 ub = __builtin_bit_cast(u32, b);
  ub += 0x7FFFu + ((ub >> 16) & 1u);
  return (ua >> 16) | (ub & 0xFFFF0000u);
}

__device__ __forceinline__ void load_lds16(const u16* g, u16* l) {
  __builtin_amdgcn_global_load_lds((const __attribute__((address_space(1))) void*)g,
                                   (__attribute__((address_space(3))) void*)l, 16, 0, 0);
}

// ---------------- transpose + fp32->bf16: src[R][C] -> dst[C][R] ----------------
__global__ __launch_bounds__(256) void tconv_kernel(const float* __restrict__ src,
                                                    u16* __restrict__ dst, int R, int C) {
  __shared__ float tile[32][33];
  int bx = blockIdx.x * 32, by = blockIdx.y * 32;
  int tx = threadIdx.x, ty = threadIdx.y;
#pragma unroll
  for (int i = 0; i < 4; ++i)
    tile[ty + 8 * i][tx] = src[(size_t)(by + ty + 8 * i) * C + bx + tx];
  __syncthreads();
#pragma unroll
  for (int i = 0; i < 4; ++i)
    dst[(size_t)(bx + ty + 8 * i) * R + by + tx] = f2bf(tile[tx][ty + 8 * i]);
}

// ---------------- LayerNorm row of 1024: fp32 in -> bf16 out ----------------
__global__ __launch_bounds__(256) void ln_kernel(const float* __restrict__ src,
                                                 u16* __restrict__ dst,
                                                 const float* __restrict__ gamma,
                                                 const float* __restrict__ beta) {
  int row = blockIdx.x, tid = threadIdx.x;
  const float4 v = ((const float4*)(src + (size_t)row * 1024))[tid];
  float s = v.x + v.y + v.z + v.w;
  float q = v.x * v.x + v.y * v.y + v.z * v.z + v.w * v.w;
#pragma unroll
  for (int off = 32; off >= 1; off >>= 1) {
    s += __shfl_down(s, off, 64);
    q += __shfl_down(q, off, 64);
  }
  __shared__ float red[8];
  if ((tid & 63) == 0) { red[(tid >> 6) * 2] = s; red[(tid >> 6) * 2 + 1] = q; }
  __syncthreads();
  s = red[0] + red[2] + red[4] + red[6];
  q = red[1] + red[3] + red[5] + red[7];
  float mean = s * (1.0f / 1024.0f);
  float var = q * (1.0f / 1024.0f) - mean * mean;
  float rstd = rsqrtf(var + 1e-5f);
  float4 g = ((const float4*)gamma)[tid];
  float4 b = ((const float4*)beta)[tid];
  ushort4 o;
  o.x = f2bf((v.x - mean) * rstd * g.x + b.x);
  o.y = f2bf((v.y - mean) * rstd * g.y + b.y);
  o.z = f2bf((v.z - mean) * rstd * g.z + b.z);
  o.w = f2bf((v.w - mean) * rstd * g.w + b.w);
  *(ushort4*)(dst + (size_t)row * 1024 + tid * 4) = o;
}

// shared epilogue
template <int MODE>
__device__ __forceinline__ void epilogue_elem(float v, int row, int col, int N,
                                              const float* __restrict__ bias,
                                              const float* __restrict__ resid,
                                              void* __restrict__ outp,
                                              void* __restrict__ outp2,
                                              void* __restrict__ outp3) {
  if constexpr (MODE == 0) {
    const int slotc = col >> 6;      // 0..47
    const int ty = slotc >> 4;       // 0=Q,1=K,2=V
    const int h = slotc & 15, d = col & 63;
    const int bb = row >> 11, s = row & 2047;
    if (ty == 0) {
      ((u16*)outp)[(((size_t)(bb * 16 + h)) * 2048 + s) * 64 + d] = f2bf(v * QSCALE);
    } else if (ty == 1) {
      ((u16*)outp2)[(((size_t)(bb * 16 + h)) * 2048 + s) * 64 + d] = f2bf(v);
    } else {
      const int spos = (s & ~31) | ((s & 15) << 1) | ((s >> 4) & 1);
      ((u16*)outp3)[(((size_t)(bb * 16 + h)) * 64 + d) * 2048 + spos] = f2bf(v);
    }
  } else if constexpr (MODE == 3) {
    ((float*)outp)[(size_t)row * N + col] = v + bias[col] + resid[(size_t)row * N + col];
  } else if constexpr (MODE == 4) {
    // gelu_tanh(u) = u * sigmoid(2c), c = 0.79788456*u*(1+0.044715*u^2)
    float u = v + bias[col];
    float c = u * (0.7978845608f + 0.0356774081f * u * u);
    float t = FEXP2(c * -2.885390082f);  // exp(-2c)
    ((u16*)outp)[(size_t)row * N + col] = f2bf(u * FRCP(1.0f + t));
  } else if constexpr (MODE == 5) {
    ((float*)outp)[(size_t)row * N + col] = v + bias[col] + resid[(size_t)row * N + col];
  }
}

// -------- staged GEMM: 128 x BN tile, BK=64 as two m97-layout 32-K halves --------
template <int MODE, int BN>
__global__ __launch_bounds__(256, 2) void gemm2(const u16* __restrict__ A,
                                                const u16* __restrict__ BT,
                                                int M, int N, int K, int nbx,
                                                const float* __restrict__ bias,
                                                const float* __restrict__ resid,
                                                void* __restrict__ outp,
                                                void* __restrict__ outp2,
                                                void* __restrict__ outp3) {
  constexpr int NJ = BN / 32;  // j-fragments per wave
  const int tid = threadIdx.x, lane = tid & 63, wave = tid >> 6;
  const int l16 = lane & 15, quad = lane >> 4;
  const int id = blockIdx.x, xcd = id & 7, s = id >> 3;
  const int by = xcd * 4 + s / nbx, bx = s - (s / nbx) * nbx;
  const int mblk = by * 128, nblk = bx * BN;
  const int m0w = (wave >> 1) * 64, n0w = (wave & 1) * (BN / 2);

  __shared__ u16 Ab[2][128 * 32];
  __shared__ u16 Bb[2][BN * 32];

  f32x4 acc[4][NJ];
#pragma unroll
  for (int i = 0; i < 4; ++i)
#pragma unroll
    for (int j = 0; j < NJ; ++j)
#pragma unroll
      for (int r = 0; r < 4; ++r) acc[i][j][r] = 0.0f;

  const int srow = lane >> 2, schunk = lane & 3;
  const u16* gA = A + (size_t)(mblk + wave * 32 + srow) * K + schunk * 8;
  u16* lA0 = Ab[0] + (wave * 32) * 32;
  u16* lA1 = Ab[1] + (wave * 32) * 32;
  const int bwrows = (BN == 128) ? wave * 32 : wave * 16;
  const u16* gB = BT + (size_t)(nblk + bwrows + srow) * K + schunk * 8;
  u16* lB0 = Bb[0] + bwrows * 32;
  u16* lB1 = Bb[1] + bwrows * 32;

  for (int k0 = 0; k0 < K; k0 += 64) {
    __syncthreads();
    load_lds16(gA + k0, lA0);
    load_lds16(gA + 16 * (size_t)K + k0, lA0 + 16 * 32);
    load_lds16(gA + k0 + 32, lA1);
    load_lds16(gA + 16 * (size_t)K + k0 + 32, lA1 + 16 * 32);
    if constexpr (BN == 128) {
      load_lds16(gB + k0, lB0);
      load_lds16(gB + 16 * (size_t)K + k0, lB0 + 16 * 32);
      load_lds16(gB + k0 + 32, lB1);
      load_lds16(gB + 16 * (size_t)K + k0 + 32, lB1 + 16 * 32);
    } else {
      load_lds16(gB + k0, lB0);
      load_lds16(gB + k0 + 32, lB1);
    }
    asm volatile("s_waitcnt vmcnt(0)" ::: "memory");
    __syncthreads();

#pragma unroll
    for (int h = 0; h < 2; ++h) {
      bf16x8 af[4], bfr[NJ];
#pragma unroll
      for (int i = 0; i < 4; ++i)
        af[i] = *(const bf16x8*)(Ab[h] + (m0w + i * 16 + l16) * 32 + quad * 8);
#pragma unroll
      for (int j = 0; j < NJ; ++j)
        bfr[j] = *(const bf16x8*)(Bb[h] + (n0w + j * 16 + l16) * 32 + quad * 8);
#pragma unroll
      for (int i = 0; i < 4; ++i)
#pragma unroll
        for (int j = 0; j < NJ; ++j)
          acc[i][j] = __builtin_amdgcn_mfma_f32_16x16x32_bf16(af[i], bfr[j], acc[i][j], 0, 0, 0);
    }
  }

#pragma unroll
  for (int i = 0; i < 4; ++i)
#pragma unroll
    for (int j = 0; j < NJ; ++j) {
      const int col = nblk + n0w + j * 16 + l16;
#pragma unroll
      for (int r = 0; r < 4; ++r)
        epilogue_elem<MODE>(acc[i][j][r], mblk + m0w + i * 16 + quad * 4 + r, col, N,
                            bias, resid, outp, outp2, outp3);
    }
}

// ---------------- attention helpers ----------------
__device__ __forceinline__ void qk_scores(const bf16x8 (&qf)[2][2],
                                          const bf16x8 (&kf)[2][2],
                                          f32x4 (&sc)[2][2]) {
#pragma unroll
  for (int rf = 0; rf < 2; ++rf)
#pragma unroll
    for (int st = 0; st < 2; ++st) {
#pragma unroll
      for (int r = 0; r < 4; ++r) sc[rf][st][r] = 0.0f;
#pragma unroll
      for (int kk = 0; kk < 2; ++kk)
        sc[rf][st] = __builtin_amdgcn_mfma_f32_16x16x32_bf16(qf[rf][kk], kf[st][kk], sc[rf][st], 0, 0, 0);
    }
}

__device__ __forceinline__ void emit_exp(const f32x4 (&sc)[2][2], bool masked,
                                         int l16, int quad, u16* pw) {
#pragma unroll
  for (int rf = 0; rf < 2; ++rf)
#pragma unroll
    for (int r = 0; r < 4; ++r) {
      float s0 = sc[rf][0][r], s1 = sc[rf][1][r];
      if (masked) {
        const int rel = rf * 16 + quad * 4 + r;
        if (l16 > rel) s0 = -INFINITY;
        if (16 + l16 > rel) s1 = -INFINITY;
      }
      *(u32*)(pw + (rf * 16 + quad * 4 + r) * 40 + l16 * 2) =
          pack2_bf16(FEXP2(s0), FEXP2(s1));
    }
}

// One pipeline stage with COMPILE-TIME buffer index (round-8 bug: runtime index
// demoted the K/V register double-buffers to scratch -> 56x regression).
template <int CUR>
__device__ __forceinline__ void attn_step(int kt, int nfull,
                                          const bf16x8 (&qf)[2][2],
                                          bf16x8 (&kfb)[2][2][2], bf16x8 (&vfb)[2][4],
                                          f32x4 (&sc)[2][2], f32x4 (&o)[2][4],
                                          f32x4 (&lac)[2], const bf16x8& onef,
                                          u16* pbase, const u16* kp, const u16* vp,
                                          int l16, int quad) {
  u16* pwc = pbase + CUR * (32 * 40);
  u16* pwn = pbase + (CUR ^ 1) * (32 * 40);

  if (kt < nfull) qk_scores(qf, kfb[CUR ^ 1], sc);  // scores(kt+1), MFMA pipe

  asm volatile("s_waitcnt lgkmcnt(0)" ::: "memory");
#pragma unroll
  for (int rf = 0; rf < 2; ++rf) {  // PV(kt), MFMA pipe
    bf16x8 pf = *(const bf16x8*)(pwc + (rf * 16 + l16) * 40 + quad * 8);
    lac[rf] = __builtin_amdgcn_mfma_f32_16x16x32_bf16(pf, onef, lac[rf], 0, 0, 0);
#pragma unroll
    for (int dt = 0; dt < 4; ++dt)
      o[rf][dt] = __builtin_amdgcn_mfma_f32_16x16x32_bf16(pf, vfb[CUR][dt], o[rf][dt], 0, 0, 0);
  }

  if (kt < nfull) {
    const int kn = (kt + 2 <= nfull ? kt + 2 : nfull) * 32;  // prefetch tile kt+2
#pragma unroll
    for (int st = 0; st < 2; ++st)
#pragma unroll
      for (int kk = 0; kk < 2; ++kk)
        kfb[CUR][st][kk] = *(const bf16x8*)(kp + (size_t)(kn + st * 16 + l16) * 64 + kk * 32 + quad * 8);
#pragma unroll
    for (int dt = 0; dt < 4; ++dt)
      vfb[CUR][dt] = *(const bf16x8*)(vp + (size_t)(dt * 16 + l16) * 2048 + kn + quad * 8);
    emit_exp(sc, (kt + 1) == nfull, l16, quad, pwn);  // exp(kt+1), VALU overlaps
  }
}

// ---------------- flash attention: causal, HEAD_DIM=64, S=2048 ----------------
// 512 blocks x 256 threads; waves 0-1 -> q-tile (31-pr), waves 2-3 -> q-tile pr
// (uniform work). Software-pipelined K-loop, statically-indexed double buffers.
__global__ __launch_bounds__(256) void attn_kernel(const u16* __restrict__ Q,
                                                   const u16* __restrict__ Kb,
                                                   const u16* __restrict__ VT,
                                                   u16* __restrict__ ctx) {
  const int tid = threadIdx.x, lane = tid & 63, wave = tid >> 6;
  const int l16 = lane & 15, quad = lane >> 4;
  const int id = blockIdx.x, xcd = id & 7, slot = id >> 3;
  const int bh = xcd + 8 * (slot & 3);   // 4 bh per XCD -> K/V stay L2-local
  const int pr = slot >> 2;              // 0..15
  const int qt = (wave < 2) ? (31 - pr) : pr;
  const int b = bh >> 4, hh = bh & 15;
  const int q0 = qt * 64 + (wave & 1) * 32;

  const u16* qp = Q + (size_t)bh * 2048 * 64;
  const u16* kp = Kb + (size_t)bh * 2048 * 64;
  const u16* vp = VT + (size_t)bh * 64 * 2048;

  bf16x8 qf[2][2];
#pragma unroll
  for (int rf = 0; rf < 2; ++rf)
#pragma unroll
    for (int kk = 0; kk < 2; ++kk)
      qf[rf][kk] = *(const bf16x8*)(qp + (size_t)(q0 + rf * 16 + l16) * 64 + kk * 32 + quad * 8);

  f32x4 o[2][4], lac[2];
#pragma unroll
  for (int rf = 0; rf < 2; ++rf) {
#pragma unroll
    for (int r = 0; r < 4; ++r) lac[rf][r] = 0.0f;
#pragma unroll
    for (int dt = 0; dt < 4; ++dt)
#pragma unroll
      for (int r = 0; r < 4; ++r) o[rf][dt][r] = 0.0f;
  }

  bf16x8 onef;
#pragma unroll
  for (int i = 0; i < 8; ++i) onef[i] = (__bf16)1.0f;

  __shared__ u16 pbuf[4][2][32 * 40];  // per-wave double-buffered P tile (20 KB)
  u16* pbase = pbuf[wave][0];

  const int nfull = q0 >> 5;  // tiles [0, nfull) unmasked; tile nfull is diagonal

  // K/V register double-buffers, 2-deep prefetch (all indices compile-time)
  bf16x8 kfb[2][2][2], vfb[2][4];
#pragma unroll
  for (int st = 0; st < 2; ++st)
#pragma unroll
    for (int kk = 0; kk < 2; ++kk)
      kfb[0][st][kk] = *(const bf16x8*)(kp + (size_t)(st * 16 + l16) * 64 + kk * 32 + quad * 8);
#pragma unroll
  for (int dt = 0; dt < 4; ++dt)
    vfb[0][dt] = *(const bf16x8*)(vp + (size_t)(dt * 16 + l16) * 2048 + quad * 8);
  const int t1 = (nfull >= 1) ? 32 : 0;
#pragma unroll
  for (int st = 0; st < 2; ++st)
#pragma unroll
    for (int kk = 0; kk < 2; ++kk)
      kfb[1][st][kk] = *(const bf16x8*)(kp + (size_t)(t1 + st * 16 + l16) * 64 + kk * 32 + quad * 8);
#pragma unroll
  for (int dt = 0; dt < 4; ++dt)
    vfb[1][dt] = *(const bf16x8*)(vp + (size_t)(dt * 16 + l16) * 2048 + t1 + quad * 8);

  f32x4 sc[2][2];
  qk_scores(qf, kfb[0], sc);
  emit_exp(sc, nfull == 0, l16, quad, pbase);

  for (int kt = 0; kt <= nfull; kt += 2) {
    attn_step<0>(kt, nfull, qf, kfb, vfb, sc, o, lac, onef, pbase, kp, vp, l16, quad);
    if (kt + 1 <= nfull)
      attn_step<1>(kt + 1, nfull, qf, kfb, vfb, sc, o, lac, onef, pbase, kp, vp, l16, quad);
  }

#pragma unroll
  for (int rf = 0; rf < 2; ++rf)
#pragma unroll
    for (int r = 0; r < 4; ++r) {
      const float inv = 1.0f / lac[rf][r];
      const int row = q0 + rf * 16 + quad * 4 + r;
#pragma unroll
      for (int dt = 0; dt < 4; ++dt) {
        const int col = dt * 16 + l16;
        ctx[((size_t)(b * 2048 + row)) * 1024 + hh * 64 + col] = f2bf(o[rf][dt][r] * inv);
      }
    }
}

// ---------------- launch ----------------
extern "C" void kernel_launch(void* const* d_in, const int* in_sizes, int n_in,
                              void* d_out, int out_size, void* d_ws, size_t ws_size,
                              hipStream_t stream) {
  (void)in_sizes; (void)n_in; (void)out_size; (void)ws_size;
  const float* x    = (const float*)d_in[0];
  const float* g1   = (const float*)d_in[1];
  const float* s1   = (const float*)d_in[2];
  const float* wq   = (const float*)d_in[3];
  const float* wk   = (const float*)d_in[4];
  const float* wv   = (const float*)d_in[5];
  const float* wo   = (const float*)d_in[6];
  const float* bo   = (const float*)d_in[7];
  const float* g2   = (const float*)d_in[8];
  const float* s2   = (const float*)d_in[9];
  const float* w1   = (const float*)d_in[10];
  const float* b1   = (const float*)d_in[11];
  const float* w2   = (const float*)d_in[12];
  const float* b2   = (const float*)d_in[13];

  char* ws = (char*)d_ws;
  u16* wqkvT = (u16*)(ws + 0);          // 6 MB  [3072][1024]
  u16* woT   = (u16*)(ws + 6291456);    // 2 MB
  u16* w1T   = (u16*)(ws + 8388608);    // 8 MB  [4096][1024]
  u16* w2T   = (u16*)(ws + 16777216);   // 8 MB  [1024][4096]
  u16* xn    = (u16*)(ws + 25165824);   // 8 MB  (reused as y)
  u16* qb    = (u16*)(ws + 33554432);   // 8 MB
  u16* kb    = (u16*)(ws + 41943040);   // 8 MB
  u16* vT    = (u16*)(ws + 50331648);   // 8 MB
  u16* ctx   = (u16*)(ws + 58720256);   // 8 MB
  u16* f     = (u16*)(ws + 33554432);   // 32 MB, aliases qb..ctx (dead by FFN1)
  float* h   = (float*)(ws + 67108864); // 16 MB
  u16* y     = xn;

  dim3 tb(32, 8);
  tconv_kernel<<<dim3(32, 32), tb, 0, stream>>>(wq, wqkvT, 1024, 1024);
  tconv_kernel<<<dim3(32, 32), tb, 0, stream>>>(wk, wqkvT + 1024 * 1024, 1024, 1024);
  tconv_kernel<<<dim3(32, 32), tb, 0, stream>>>(wv, wqkvT + 2048 * 1024, 1024, 1024);
  tconv_kernel<<<dim3(32, 32), tb, 0, stream>>>(wo, woT, 1024, 1024);
  tconv_kernel<<<dim3(128, 32), tb, 0, stream>>>(w1, w1T, 1024, 4096);
  tconv_kernel<<<dim3(32, 128), tb, 0, stream>>>(w2, w2T, 4096, 1024);

  // LN1
  ln_kernel<<<4096, 256, 0, stream>>>(x, xn, g1, s1);

  // fused QKV projection (N=3072), nbx=24
  gemm2<0, 128><<<768, 256, 0, stream>>>(xn, wqkvT, 4096, 3072, 1024, 24,
                                         nullptr, nullptr, qb, kb, vT);

  // attention: 512 uniform blocks, pipelined (static buffer indices)
  attn_kernel<<<512, 256, 0, stream>>>(qb, kb, vT, ctx);

  // output projection + bias + residual(x) -> h (fp32), nbx=16
  gemm2<3, 64><<<512, 256, 0, stream>>>(ctx, woT, 4096, 1024, 1024, 16, bo, x, h,
                                        nullptr, nullptr);

  // LN2
  ln_kernel<<<4096, 256, 0, stream>>>(h, y, g2, s2);

  // FFN1 (N=4096), nbx=32
  gemm2<4, 128><<<1024, 256, 0, stream>>>(y, w1T, 4096, 4096, 1024, 32,
                                          b1, nullptr, f, nullptr, nullptr);
  // FFN2 (N=1024, K=4096), nbx=16
  gemm2<5, 64><<<512, 256, 0, stream>>>(f, w2T, 4096, 1024, 4096, 16, b2, h,
                                        (float*)d_out, nullptr, nullptr);
}